// Round 2
// baseline (13192.136 us; speedup 1.0000x reference)
//
#include <hip/hip_runtime.h>
#include <cstdint>
#include <cstddef>

// ---------------------------------------------------------------------------
// Factored-LSTM  (T=512, B=128, H=1024, rank=256)
// (B_g@C_g) folded into dense W  ->  plain LSTM:
//   pre_t = W_x @ x_t + W_h @ h_{t-1} + bias,  gates f,i,g,o
// Time-chunked (Tc steps/chunk, chosen to fit ws_size):
//   per chunk: convert_x -> gemm_bt (m97 structure) -> lstm_seq (persistent,
//   W_h pinned in VGPRs, c in regs, per-batch-group global barriers).
// W'/pre_x rows are gate-interleaved: row' = hcol*4 + g so one MFMA C/D f32x4
// = the 4 gate preactivations of one (hcol, batch).
// ---------------------------------------------------------------------------

typedef unsigned short u16;
typedef __attribute__((ext_vector_type(8))) short bh8;    // 8 x bf16 (4 VGPR)
typedef __attribute__((ext_vector_type(4))) float f32x4;
typedef __attribute__((ext_vector_type(4))) unsigned short u16x4;

#define T_STEPS 512
#define BATCH   128
#define HID     1024
#define N4      4096

__device__ __forceinline__ u16 f2bf(float f) {
  unsigned u = __float_as_uint(f);
  u += 0x7FFFu + ((u >> 16) & 1u);          // RNE
  return (u16)(u >> 16);
}
__device__ __forceinline__ float sigm(float x) { return 1.f / (1.f + __expf(-x)); }
__device__ __forceinline__ float tanh_f(float x) {
  float ax = fabsf(x);
  float e = __expf(-2.f * ax);
  float t = (1.f - e) / (1.f + e);
  return copysignf(t, x);
}
__device__ __forceinline__ void async16(const u16* g, u16* l) {
  __builtin_amdgcn_global_load_lds((const __attribute__((address_space(1))) void*)g,
                                   (__attribute__((address_space(3))) void*)l, 16, 0, 0);
}

// ---------------------------------------------------------------------------
// prep_misc: A rows -> W' bf16 (interleaved), h0 -> bf16, bias', bar=0,
// c0 -> cbuf. exact grid: 594432 items / 256 = 2322 blocks
// ---------------------------------------------------------------------------
__global__ void __launch_bounds__(256) prep_misc(
    const float* __restrict__ Ax, const float* __restrict__ Ah,
    const float* __restrict__ bx, const float* __restrict__ bh,
    const float* __restrict__ h0, const float* __restrict__ c0,
    u16* __restrict__ Wx, u16* __restrict__ Wh,
    float* __restrict__ bias2, u16* __restrict__ hb0,
    float* __restrict__ cbuf, unsigned* __restrict__ bar) {
  unsigned idx = blockIdx.x * 256 + threadIdx.x;
  if (idx < 524288) {                       // A_x / A_h rich rows (vec4 over k)
    bool isH = idx >= 262144;
    unsigned i = idx & 262143;
    unsigned row = i >> 8, k4 = i & 255;    // row = g*256+hcol
    unsigned g = row >> 8, hcol = row & 255;
    unsigned rowp = hcol * 4 + g;
    const float* src = (isH ? Ah : Ax) + (size_t)row * 1024 + k4 * 4;
    u16* dst = (isH ? Wh : Wx) + (size_t)rowp * 1024 + k4 * 4;
    f32x4 v = *(const f32x4*)src;
    u16x4 o; o[0]=f2bf(v[0]); o[1]=f2bf(v[1]); o[2]=f2bf(v[2]); o[3]=f2bf(v[3]);
    *(u16x4*)dst = o;
  } else if (idx < 557056) {                // h0 -> bf16
    unsigned i4 = idx - 524288;
    f32x4 v = *(const f32x4*)(h0 + (size_t)i4 * 4);
    u16x4 o; o[0]=f2bf(v[0]); o[1]=f2bf(v[1]); o[2]=f2bf(v[2]); o[3]=f2bf(v[3]);
    *(u16x4*)(hb0 + (size_t)i4 * 4) = o;
  } else if (idx < 561152) {                // bias' (interleaved)
    unsigned i = idx - 557056;
    unsigned hcol = i >> 2, g = i & 3;
    bias2[i] = bx[g * 1024 + hcol] + bh[g * 1024 + hcol];
  } else if (idx < 561664) {                // zero barrier counters (512 u32)
    bar[idx - 561152] = 0u;
  } else {                                  // c0 -> cbuf (f32 copy)
    unsigned i4 = idx - 561664;             // < 32768
    f32x4 v = *(const f32x4*)(c0 + (size_t)i4 * 4);
    *(f32x4*)(cbuf + (size_t)i4 * 4) = v;
  }
}

// ---------------------------------------------------------------------------
// bc_gemm: W'_sparse[(256+m)*4+g] = (B_g @ C_g)[m, :]  f32 acc, stored bf16.
// grid (16, 24, 8): d-tiles of 64, m-tiles of 32, z = branch*4+gate
// ---------------------------------------------------------------------------
__global__ void __launch_bounds__(256) bc_gemm(
    const float* __restrict__ Bx, const float* __restrict__ Cx,
    const float* __restrict__ Bh, const float* __restrict__ Ch,
    u16* __restrict__ Wx, u16* __restrict__ Wh) {
  int z = blockIdx.z, g = z & 3;
  const float* Bp = ((z >= 4) ? Bh : Bx) + (size_t)g * 768 * 256;
  const float* Cp = ((z >= 4) ? Ch : Cx) + (size_t)g * 256 * 1024;
  u16* Wp = (z >= 4) ? Wh : Wx;
  int m0 = blockIdx.y * 32, d0 = blockIdx.x * 64;
  int tid = threadIdx.x;
  __shared__ float Bs[32][68];
  __shared__ float Cs[64][64];
  int dt = tid & 63, mt = tid >> 6;
  float acc[8] = {0.f,0.f,0.f,0.f,0.f,0.f,0.f,0.f};
  for (int kc = 0; kc < 256; kc += 64) {
#pragma unroll
    for (int i = 0; i < 2; i++) {           // Bs: 32x64
      int id4 = i * 256 + tid;
      int r = id4 >> 4, c4 = id4 & 15;
      f32x4 v = *(const f32x4*)(Bp + (size_t)(m0 + r) * 256 + kc + c4 * 4);
      *(f32x4*)&Bs[r][c4 * 4] = v;
    }
#pragma unroll
    for (int i = 0; i < 4; i++) {           // Cs: 64x64
      int id4 = i * 256 + tid;
      int r = id4 >> 4, c4 = id4 & 15;
      f32x4 v = *(const f32x4*)(Cp + (size_t)(kc + r) * 1024 + d0 + c4 * 4);
      *(f32x4*)&Cs[r][c4 * 4] = v;
    }
    __syncthreads();
#pragma unroll
    for (int k = 0; k < 64; k++) {
      float cv = Cs[k][dt];
#pragma unroll
      for (int mi = 0; mi < 8; mi++) acc[mi] += Bs[mt + mi * 4][k] * cv;
    }
    __syncthreads();
  }
#pragma unroll
  for (int mi = 0; mi < 8; mi++) {
    int m = m0 + mt + mi * 4;
    int rowp = (256 + m) * 4 + g;
    Wp[(size_t)rowp * 1024 + d0 + dt] = f2bf(acc[mi]);
  }
}

// ---------------------------------------------------------------------------
// convert_x: f32 -> bf16, 8 elems/thread (chunk of Tc steps)
// ---------------------------------------------------------------------------
__global__ void __launch_bounds__(256) convert_x(const float* __restrict__ x,
                                                 u16* __restrict__ xb) {
  size_t i = (size_t)blockIdx.x * 256 + threadIdx.x;
  f32x4 a = *(const f32x4*)(x + i * 8);
  f32x4 b = *(const f32x4*)(x + i * 8 + 4);
  u16x4 oa, ob;
  oa[0]=f2bf(a[0]); oa[1]=f2bf(a[1]); oa[2]=f2bf(a[2]); oa[3]=f2bf(a[3]);
  ob[0]=f2bf(b[0]); ob[1]=f2bf(b[1]); ob[2]=f2bf(b[2]); ob[3]=f2bf(b[3]);
  *(u16x4*)(xb + i * 8) = oa;
  *(u16x4*)(xb + i * 8 + 4) = ob;
}

// ---------------------------------------------------------------------------
// gemm_bt: C[M,N] = A[M,K] * B[N,K]^T   (m97: 128x128 tile, BK=32,
// global_load_lds width16, 16x16x32 bf16 MFMA, 4 waves, 4x4 tiles/wave)
// ---------------------------------------------------------------------------
__global__ void __launch_bounds__(256, 2) gemm_bt(
    const u16* __restrict__ A, const u16* __restrict__ Bm,
    float* __restrict__ C, int M, int N, int K) {
  __shared__ u16 As[128 * 32];
  __shared__ u16 Bs[128 * 32];
  int tid = threadIdx.x;
  int m0 = blockIdx.y * 128, n0 = blockIdx.x * 128;
  int w = tid >> 6, lane = tid & 63, q = lane >> 4, nl = lane & 15;
  int wm = (w & 1) * 64, wn = (w >> 1) * 64;
  f32x4 acc[4][4] = {};
  int srow = tid >> 2, skof = (tid & 3) * 8;
  const u16* pa = A + (size_t)(m0 + srow) * K + skof;
  const u16* pb = Bm + (size_t)(n0 + srow) * K + skof;
  u16* dA = (u16*)As + w * 512;
  u16* dB = (u16*)Bs + w * 512;
  for (int kt = 0; kt < K; kt += 32) {
    async16(pa + kt, dA);
    async16(pa + kt + (size_t)64 * K, dA + 2048);
    async16(pb + kt, dB);
    async16(pb + kt + (size_t)64 * K, dB + 2048);
    __syncthreads();
    bh8 af[4], bf[4];
#pragma unroll
    for (int i = 0; i < 4; i++) {
      af[i] = *(const bh8*)(As + (wm + i * 16 + nl) * 32 + q * 8);
      bf[i] = *(const bh8*)(Bs + (wn + i * 16 + nl) * 32 + q * 8);
    }
#pragma unroll
    for (int i = 0; i < 4; i++)
#pragma unroll
      for (int j = 0; j < 4; j++)
        acc[i][j] = __builtin_amdgcn_mfma_f32_16x16x32_bf16(af[i], bf[j], acc[i][j], 0, 0, 0);
    __syncthreads();
  }
#pragma unroll
  for (int i = 0; i < 4; i++)
#pragma unroll
    for (int j = 0; j < 4; j++) {
      int mr = m0 + wm + i * 16 + q * 4;
      int nc = n0 + wn + j * 16 + nl;
      float* cp = C + (size_t)mr * N + nc;
#pragma unroll
      for (int r = 0; r < 4; r++) cp[(size_t)r * N] = acc[i][j][r];
    }
}

// ---------------------------------------------------------------------------
// lstm_seq: persistent, steps [t0, t0+tcnt). 512 blocks = 64 hgrp x 8 bgrp.
// Block: 16 hcols x 16 batches. W_h pinned in 128 VGPRs. c in regs (cbuf at
// chunk seams). 8 independent per-bgrp barriers, h double-buffered (global t
// parity). pre_x indexed by (t - t0) within the chunk buffer.
// ---------------------------------------------------------------------------
__global__ void __launch_bounds__(256, 2) lstm_seq(
    const u16* __restrict__ Wh, const float* __restrict__ bias2,
    const float* __restrict__ pre_x, u16* __restrict__ hb0,
    u16* __restrict__ hb1, float* __restrict__ cbuf,
    float* __restrict__ out, unsigned* __restrict__ bar,
    int t0, int tcnt) {
  int tid = threadIdx.x;
  int w = tid >> 6, lane = tid & 63, q = lane >> 4, nl = lane & 15;
  int blk = blockIdx.x;
  int bgrp = blk & 7, hgrp = blk >> 3;
  int b0 = bgrp * 16;

  // pin W_h fragments: A-operand m = lane&15 (rowp local), k = kk*32 + q*8 + j
  bh8 wfrag[32];
  {
    const u16* wp = Wh + (size_t)(hgrp * 64 + w * 16 + nl) * 1024 + q * 8;
#pragma unroll
    for (int kk = 0; kk < 32; kk++) wfrag[kk] = *(const bh8*)(wp + kk * 32);
  }
  int hcol = hgrp * 16 + w * 4 + q;         // this lane's hidden column (C/D row q*4+g)
  int bb = b0 + nl;                          // this lane's batch (C/D col nl)
  float creg = cbuf[(size_t)bb * 1024 + hcol];
  f32x4 bsv = *(const f32x4*)(bias2 + hcol * 4);

  __shared__ u16 hls[16 * 1032];            // 16 batches x 1024 (+8 pad)
  unsigned* cnt = bar + bgrp * 64;          // 256B-spaced counters

  for (int t = t0; t < t0 + tcnt; t++) {
    const u16* hread = (t & 1) ? hb1 : hb0;
    u16* hwrite = (t & 1) ? hb0 : hb1;
    f32x4 pxv = *(const f32x4*)(pre_x + ((size_t)(t - t0) * 128 + bb) * 4096 + hcol * 4);
    // stage h tile into LDS: 16 rows x 1024 bf16
#pragma unroll
    for (int i = 0; i < 8; i++) {
      int chunk = i * 256 + tid;
      int r = chunk >> 7, cc = chunk & 127;
      bh8 v = *(const bh8*)(hread + (size_t)(b0 + r) * 1024 + cc * 8);
      *(bh8*)(hls + r * 1032 + cc * 8) = v;
    }
    __syncthreads();
    f32x4 acc0 = {0.f,0.f,0.f,0.f}, acc1 = {0.f,0.f,0.f,0.f};
#pragma unroll
    for (int kk = 0; kk < 32; kk += 2) {
      bh8 hv0 = *(const bh8*)(hls + nl * 1032 + kk * 32 + q * 8);
      bh8 hv1 = *(const bh8*)(hls + nl * 1032 + (kk + 1) * 32 + q * 8);
      acc0 = __builtin_amdgcn_mfma_f32_16x16x32_bf16(wfrag[kk], hv0, acc0, 0, 0, 0);
      acc1 = __builtin_amdgcn_mfma_f32_16x16x32_bf16(wfrag[kk + 1], hv1, acc1, 0, 0, 0);
    }
    // epilogue: acc regs 0..3 = gates f,i,g,o of (hcol, bb)
    float pf = acc0[0] + acc1[0] + pxv[0] + bsv[0];
    float pi = acc0[1] + acc1[1] + pxv[1] + bsv[1];
    float pg = acc0[2] + acc1[2] + pxv[2] + bsv[2];
    float po = acc0[3] + acc1[3] + pxv[3] + bsv[3];
    float f = sigm(pf), ii = sigm(pi), gg = tanh_f(pg), o = sigm(po);
    float c = f * creg + ii * gg;
    creg = c;
    float h = o * tanh_f(c);
    out[(size_t)t * 131072 + (size_t)bb * 1024 + hcol] = h;
    hwrite[(size_t)bb * 1024 + hcol] = f2bf(h);
    if (t == T_STEPS - 1) {
      out[67108864 + (size_t)bb * 1024 + hcol] = h;
      out[67108864 + 131072 + (size_t)bb * 1024 + hcol] = c;
    }
    // per-batch-group barrier (64 blocks), skipped only at the very last step
    if (t < T_STEPS - 1) {
      __syncthreads();
      if (tid == 0) {
        __hip_atomic_fetch_add(cnt, 1u, __ATOMIC_RELEASE, __HIP_MEMORY_SCOPE_AGENT);
        unsigned tgt = 64u * (unsigned)(t + 1);
        while (__hip_atomic_load(cnt, __ATOMIC_RELAXED, __HIP_MEMORY_SCOPE_AGENT) < tgt)
          __builtin_amdgcn_s_sleep(2);
        (void)__hip_atomic_load(cnt, __ATOMIC_ACQUIRE, __HIP_MEMORY_SCOPE_AGENT);
      }
      __syncthreads();
    }
  }
  cbuf[(size_t)bb * 1024 + hcol] = creg;    // persist c across chunk seams
}

// ---------------------------------------------------------------------------
extern "C" void kernel_launch(void* const* d_in, const int* in_sizes, int n_in,
                              void* d_out, int out_size, void* d_ws, size_t ws_size,
                              hipStream_t stream) {
  const float* x  = (const float*)d_in[0];
  const float* h0 = (const float*)d_in[1];
  const float* c0 = (const float*)d_in[2];
  const float* Ax = (const float*)d_in[3];
  const float* Bx = (const float*)d_in[4];
  const float* Cx = (const float*)d_in[5];
  const float* Ah = (const float*)d_in[6];
  const float* Bh = (const float*)d_in[7];
  const float* Ch = (const float*)d_in[8];
  const float* bx = (const float*)d_in[9];
  const float* bh = (const float*)d_in[10];
  float* out = (float*)d_out;

  // fixed footprint: Wx+Wh 16MiB, bias 16KiB, hb0/hb1 512KiB, cbuf 512KiB, bar 4KiB
  const size_t fixed = (size_t)N4 * 1024 * 2 * 2 + (size_t)N4 * 4
                     + (size_t)2 * BATCH * HID * 2 + (size_t)BATCH * HID * 4 + 4096;
  int Tc = 512;
  while (Tc > 16) {
    size_t need = fixed + (size_t)Tc * 128 * 4096 * 4 + (size_t)Tc * 128 * 1024 * 2;
    if (need <= ws_size) break;
    Tc >>= 1;
  }
  if (fixed + (size_t)Tc * 128 * 4096 * 4 + (size_t)Tc * 128 * 1024 * 2 > ws_size)
    return;                                 // < ~53 MiB workspace: cannot run

  char* p = (char*)d_ws;
  float* pre_x = (float*)p;            p += (size_t)Tc * 128 * 4096 * 4;
  u16* x_bf    = (u16*)p;              p += (size_t)Tc * 128 * 1024 * 2;
  u16* Wx      = (u16*)p;              p += (size_t)N4 * 1024 * 2;
  u16* Wh      = (u16*)p;              p += (size_t)N4 * 1024 * 2;
  float* bias2 = (float*)p;            p += (size_t)N4 * 4;
  u16* hb0     = (u16*)p;              p += (size_t)BATCH * HID * 2;
  u16* hb1     = (u16*)p;              p += (size_t)BATCH * HID * 2;
  float* cbuf  = (float*)p;            p += (size_t)BATCH * HID * 4;
  unsigned* bar = (unsigned*)p;        p += 4096;

  prep_misc<<<2322, 256, 0, stream>>>(Ax, Ah, bx, bh, h0, c0, Wx, Wh, bias2, hb0, cbuf, bar);
  bc_gemm<<<dim3(16, 24, 8), 256, 0, stream>>>(Bx, Cx, Bh, Ch, Wx, Wh);
  for (int t0 = 0; t0 < T_STEPS; t0 += Tc) {
    convert_x<<<Tc * 64, 256, 0, stream>>>(x + (size_t)t0 * 131072, x_bf);
    gemm_bt<<<dim3(N4 / 128, Tc), 256, 0, stream>>>(x_bf, Wx, pre_x, Tc * 128, N4, 1024);
    lstm_seq<<<512, 256, 0, stream>>>(Wh, bias2, pre_x, hb0, hb1, cbuf, out, bar, t0, Tc);
  }
}